// Round 4
// baseline (145.886 us; speedup 1.0000x reference)
//
#include <hip/hip_runtime.h>

#define F 128
#define S 25
#define CH 8      // column chunks
#define CW 16     // cols per chunk (32 B bf16 rows -> 3.2 MB slice, fits 4 MB XCD L2)

typedef __attribute__((ext_vector_type(8))) short bf16x8;
typedef __attribute__((ext_vector_type(4))) float f32x4;
typedef __attribute__((ext_vector_type(2))) float f32x2;   // native vec for nontemporal

// round-to-nearest-even f32 -> bf16 bits
__device__ __forceinline__ ushort f2bf(float f) {
    uint u = __float_as_uint(f);
    return (ushort)((u + 0x7FFFu + ((u >> 16) & 1u)) >> 16);
}
__device__ __forceinline__ float bf_lo(uint v) { return __uint_as_float(v << 16); }
__device__ __forceinline__ float bf_hi(uint v) { return __uint_as_float(v & 0xFFFF0000u); }

// neighbor_idx may arrive as int32 or int64. int64 LE with values < 2^31 has
// all odd dwords zero. Deterministic data probe.
__device__ __forceinline__ bool idx_is_i64(const int* __restrict__ p) {
    return (p[1] | p[3] | p[5] | p[7]) == 0;
}
__device__ __forceinline__ int load_idx(const int* __restrict__ p, size_t i, bool is64) {
    return is64 ? p[2 * i] : p[i];
}

// ---------------------------------------------------------------------------
// K0: compact neighbor_idx to int32 (idx re-streamed 8x in K2; halve the bytes)
// ---------------------------------------------------------------------------
__global__ __launch_bounds__(256) void compact_idx(
    const int* __restrict__ src, int* __restrict__ dst, int M)
{
    const bool is64 = idx_is_i64(src);
    int e = blockIdx.x * 256 + threadIdx.x;
    if (e < M) dst[e] = load_idx(src, (size_t)e, is64);
}

// ---------------------------------------------------------------------------
// K1: y = bf16(x) @ bf16(W) via v_mfma_f32_16x16x32_bf16 (fp32 accum).
// CHUNKED=1 writes y[(nt*N + row)*16 + col] (K2's chunk layout), else row-major.
// W staged in LDS in exact B-fragment order -> linear ds_read_b128.
// Layouts (learn_hip m89/m91): A row=lane&15, k=8*(lane>>4)+b;
//                              D col=lane&15, row=4*(lane>>4)+reg.
// ---------------------------------------------------------------------------
template <int CHUNKED>
__global__ __launch_bounds__(256) void gemm_xw_bf16(
    const float* __restrict__ x, const float* __restrict__ W,
    ushort* __restrict__ y, int N)
{
    __shared__ ushort WF[4][8][64][8];   // 32 KB

    const int tid  = threadIdx.x;
    const int lane = tid & 63;
    const int wid  = tid >> 6;

    for (int e = tid; e < 4 * 8 * 64; e += 256) {
        const int l  = e & 63;
        const int nt = (e >> 6) & 7;
        const int kt = e >> 9;
        const int k0 = kt * 32 + (l >> 4) * 8;
        const int n  = nt * 16 + (l & 15);
        #pragma unroll
        for (int b = 0; b < 8; ++b)
            WF[kt][nt][l][b] = f2bf(W[(size_t)(k0 + b) * F + n]);
    }
    __syncthreads();

    const int n0 = blockIdx.x * 64 + wid * 16;
    const int arow = n0 + (lane & 15);
    const int arow_c = arow < N ? arow : N - 1;
    const float* xrow = x + (size_t)arow_c * F + (lane >> 4) * 8;

    f32x4 acc[8];
    #pragma unroll
    for (int nt = 0; nt < 8; ++nt) acc[nt] = (f32x4){0.f, 0.f, 0.f, 0.f};

    #pragma unroll
    for (int kt = 0; kt < 4; ++kt) {
        float4 a0 = *(const float4*)(xrow + kt * 32);
        float4 a1 = *(const float4*)(xrow + kt * 32 + 4);
        bf16x8 af;
        af[0] = (short)f2bf(a0.x); af[1] = (short)f2bf(a0.y);
        af[2] = (short)f2bf(a0.z); af[3] = (short)f2bf(a0.w);
        af[4] = (short)f2bf(a1.x); af[5] = (short)f2bf(a1.y);
        af[6] = (short)f2bf(a1.z); af[7] = (short)f2bf(a1.w);
        #pragma unroll
        for (int nt = 0; nt < 8; ++nt) {
            bf16x8 bf = *(const bf16x8*)&WF[kt][nt][lane][0];
            acc[nt] = __builtin_amdgcn_mfma_f32_16x16x32_bf16(af, bf, acc[nt], 0, 0, 0);
        }
    }

    const int drow0 = n0 + (lane >> 4) * 4;
    const int dcol  = lane & 15;
    #pragma unroll
    for (int nt = 0; nt < 8; ++nt) {
        #pragma unroll
        for (int r = 0; r < 4; ++r) {
            const int row = drow0 + r;
            if (row < N) {
                if (CHUNKED)
                    y[((size_t)nt * N + row) * CW + dcol] = f2bf(acc[nt][r]);
                else
                    y[(size_t)row * F + nt * 16 + dcol] = f2bf(acc[nt][r]);
            }
        }
    }
}

// ---------------------------------------------------------------------------
// K2: chunked gather-average. chunk = blockIdx & 7 -> rides the HW round-robin
// block->XCD mapping so each XCD's L2 caches exactly its 3.2 MB y-slice.
// Block = 64 nodes; wave = 8 nodes x 8 lanes (lane j covers 2 cols as 1 dword).
// idx staged in LDS; idx loads + out stores nontemporal (don't pollute L2).
// ---------------------------------------------------------------------------
__global__ __launch_bounds__(256) void gather_chunked(
    const ushort* __restrict__ y, const int* __restrict__ idx32,
    const float* __restrict__ bias, float* __restrict__ out, int N)
{
    __shared__ int IDX[64 * S];

    const int tid   = threadIdx.x;
    const int chunk = blockIdx.x & 7;
    const int tile  = blockIdx.x >> 3;
    const int nbase = tile * 64;
    const long total = (long)N * S;

    for (int e = tid; e < 64 * S; e += 256) {
        long p = (long)nbase * S + e;
        IDX[e] = (p < total) ? __builtin_nontemporal_load(&idx32[p]) : 0;
    }
    __syncthreads();

    const int lane = tid & 63, wave = tid >> 6;
    const int g = lane >> 3, j = lane & 7;
    const float2 bb = *(const float2*)(bias + chunk * CW + 2 * j);
    const float inv = 1.0f / (float)(S + 1);
    const char* ycb = (const char*)(y + (size_t)chunk * N * CW);

    #pragma unroll
    for (int oct = 0; oct < 2; ++oct) {
        const int nl = wave * 16 + oct * 8 + g;   // node within tile
        const int n  = nbase + nl;
        const int nc = n < N ? n : 0;

        uint v[26];
        v[25] = *(const uint*)(ycb + (((uint)nc) << 5) + (j << 2));   // self
        #pragma unroll
        for (int s = 0; s < S; ++s) {
            int id = IDX[nl * S + s];
            v[s] = *(const uint*)(ycb + (((uint)id) << 5) + (j << 2));
        }

        float ax = 0.f, ay = 0.f;
        #pragma unroll
        for (int s = 0; s < 26; ++s) { ax += bf_lo(v[s]); ay += bf_hi(v[s]); }

        if (n < N) {
            f32x2 o;
            o.x = ax * inv + bb.x;
            o.y = ay * inv + bb.y;
            __builtin_nontemporal_store(o, (f32x2*)(out + (size_t)n * F + chunk * CW + 2 * j));
        }
    }
}

// ---------------------------------------------------------------------------
// Fallback A (ws fits y only): round-2 flat gather on row-major bf16 y.
// ---------------------------------------------------------------------------
__global__ __launch_bounds__(256) void gather_agg_bf16(
    const ushort* __restrict__ y, const int* __restrict__ nbr,
    const float* __restrict__ bias, float* __restrict__ out, int N)
{
    const int lane = threadIdx.x & 63;
    const int wid  = threadIdx.x >> 6;
    const bool is64 = idx_is_i64(nbr);
    const float2 bb = ((const float2*)bias)[lane];
    const float inv = 1.0f / (float)(S + 1);
    const int nw = gridDim.x * 4;
    const uint* yw = (const uint*)y;

    for (int n = blockIdx.x * 4 + wid; n < N; n += nw) {
        const int nu = __builtin_amdgcn_readfirstlane(n);
        int ids[S];
        #pragma unroll
        for (int s = 0; s < S; ++s)
            ids[s] = load_idx(nbr, (size_t)nu * S + s, is64);
        uint vs[S];
        #pragma unroll
        for (int s = 0; s < S; ++s)
            vs[s] = yw[(size_t)ids[s] * 64 + lane];
        const uint v0 = yw[(size_t)nu * 64 + lane];
        float ax = bf_lo(v0), ay = bf_hi(v0);
        #pragma unroll
        for (int s = 0; s < S; ++s) { ax += bf_lo(vs[s]); ay += bf_hi(vs[s]); }
        float2 o;
        o.x = ax * inv + bb.x;
        o.y = ay * inv + bb.y;
        ((float2*)(out + (size_t)nu * F))[lane] = o;
    }
}

// ---------------------------------------------------------------------------
// Fallback B (tiny ws): fused fp32 gather+GEMM.
// ---------------------------------------------------------------------------
__global__ __launch_bounds__(256) void fused_fallback_kernel(
    const float* __restrict__ x, const int* __restrict__ nbr,
    const float* __restrict__ W, const float* __restrict__ bias,
    float* __restrict__ out, int N)
{
    __shared__ float aggs[4][F];
    const int lane = threadIdx.x & 63;
    const int wid  = threadIdx.x >> 6;
    const bool is64 = idx_is_i64(nbr);
    const float inv = 1.0f / (float)(S + 1);
    const int stride = gridDim.x * 4;

    for (int base = blockIdx.x * 4; base < N; base += stride) {
        int n = base + wid;
        bool act = n < N;
        float2 acc = make_float2(0.f, 0.f);
        if (act) {
            acc = ((const float2*)(x + (size_t)n * F))[lane];
            for (int s = 0; s < S; ++s) {
                int id = load_idx(nbr, (size_t)n * S + s, is64);
                float2 v = ((const float2*)(x + (size_t)id * F))[lane];
                acc.x += v.x; acc.y += v.y;
            }
        }
        aggs[wid][2 * lane]     = acc.x * inv;
        aggs[wid][2 * lane + 1] = acc.y * inv;
        __syncthreads();
        if (act) {
            float o0 = bias[lane], o1 = bias[lane + 64];
            for (int k = 0; k < F; ++k) {
                float a = aggs[wid][k];
                o0 += a * W[k * F + lane];
                o1 += a * W[k * F + lane + 64];
            }
            out[(size_t)n * F + lane]      = o0;
            out[(size_t)n * F + lane + 64] = o1;
        }
        __syncthreads();
    }
}

extern "C" void kernel_launch(void* const* d_in, const int* in_sizes, int n_in,
                              void* d_out, int out_size, void* d_ws, size_t ws_size,
                              hipStream_t stream) {
    const float* x    = (const float*)d_in[0];
    const int*   nbr  = (const int*)d_in[1];
    const float* W    = (const float*)d_in[2];
    const float* bias = (const float*)d_in[3];
    float* out = (float*)d_out;
    const int N = in_sizes[0] / F;                 // 100000
    const int M = N * S;                           // 2.5M edges

    const size_t y_bytes   = (size_t)N * F * sizeof(ushort);   // 25.6 MB
    const size_t idx_bytes = (size_t)M * sizeof(int);          // 10 MB

    if (ws_size >= y_bytes + idx_bytes) {
        ushort* y   = (ushort*)d_ws;
        int*  idx32 = (int*)((char*)d_ws + y_bytes);
        compact_idx<<<(M + 255) / 256, 256, 0, stream>>>(nbr, idx32, M);
        gemm_xw_bf16<1><<<(N + 63) / 64, 256, 0, stream>>>(x, W, y, N);
        const int tiles = (N + 63) / 64;           // 1563
        gather_chunked<<<tiles * CH, 256, 0, stream>>>(y, idx32, bias, out, N);
    } else if (ws_size >= y_bytes) {
        ushort* y = (ushort*)d_ws;
        gemm_xw_bf16<0><<<(N + 63) / 64, 256, 0, stream>>>(x, W, y, N);
        gather_agg_bf16<<<2048, 256, 0, stream>>>(y, nbr, bias, out, N);
    } else {
        fused_fallback_kernel<<<2048, 256, 0, stream>>>(x, nbr, W, bias, out, N);
    }
}

// Round 5
// 116.041 us; speedup vs baseline: 1.2572x; 1.2572x over previous
//
#include <hip/hip_runtime.h>

#define F 128
#define S 25
#define CH 4      // column chunks
#define CW 32     // cols per chunk (64 B bf16 rows -> 6.4 MB slice per chunk)

typedef __attribute__((ext_vector_type(8))) short bf16x8;
typedef __attribute__((ext_vector_type(4))) float f32x4;
typedef __attribute__((ext_vector_type(2))) float f32x2;   // native vec for nontemporal

// round-to-nearest-even f32 -> bf16 bits
__device__ __forceinline__ ushort f2bf(float f) {
    uint u = __float_as_uint(f);
    return (ushort)((u + 0x7FFFu + ((u >> 16) & 1u)) >> 16);
}
__device__ __forceinline__ float bf_lo(uint v) { return __uint_as_float(v << 16); }
__device__ __forceinline__ float bf_hi(uint v) { return __uint_as_float(v & 0xFFFF0000u); }

// neighbor_idx may arrive as int32 or int64. int64 LE with values < 2^31 has
// all odd dwords zero. Deterministic data probe.
__device__ __forceinline__ bool idx_is_i64(const int* __restrict__ p) {
    return (p[1] | p[3] | p[5] | p[7]) == 0;
}
__device__ __forceinline__ int load_idx(const int* __restrict__ p, size_t i, bool is64) {
    return is64 ? p[2 * i] : p[i];
}

// ---------------------------------------------------------------------------
// K0: compact neighbor_idx to int32 (idx re-streamed CH x in K2)
// ---------------------------------------------------------------------------
__global__ __launch_bounds__(256) void compact_idx(
    const int* __restrict__ src, int* __restrict__ dst, int M)
{
    const bool is64 = idx_is_i64(src);
    int e = blockIdx.x * 256 + threadIdx.x;
    if (e < M) dst[e] = load_idx(src, (size_t)e, is64);
}

// ---------------------------------------------------------------------------
// K1: y = bf16(x) @ bf16(W) via v_mfma_f32_16x16x32_bf16 (fp32 accum).
// CHUNKED=1 writes y[((c*N + row)*CW + ccol)] with c = gcol/CW (K2's layout),
// else row-major. W staged in LDS in exact B-fragment order.
// Layouts (learn_hip m89/m91): A row=lane&15, k=8*(lane>>4)+b;
//                              D col=lane&15, row=4*(lane>>4)+reg.
// ---------------------------------------------------------------------------
template <int CHUNKED>
__global__ __launch_bounds__(256) void gemm_xw_bf16(
    const float* __restrict__ x, const float* __restrict__ W,
    ushort* __restrict__ y, int N)
{
    __shared__ ushort WF[4][8][64][8];   // 32 KB

    const int tid  = threadIdx.x;
    const int lane = tid & 63;
    const int wid  = tid >> 6;

    for (int e = tid; e < 4 * 8 * 64; e += 256) {
        const int l  = e & 63;
        const int nt = (e >> 6) & 7;
        const int kt = e >> 9;
        const int k0 = kt * 32 + (l >> 4) * 8;
        const int n  = nt * 16 + (l & 15);
        #pragma unroll
        for (int b = 0; b < 8; ++b)
            WF[kt][nt][l][b] = f2bf(W[(size_t)(k0 + b) * F + n]);
    }
    __syncthreads();

    const int n0 = blockIdx.x * 64 + wid * 16;
    const int arow = n0 + (lane & 15);
    const int arow_c = arow < N ? arow : N - 1;
    const float* xrow = x + (size_t)arow_c * F + (lane >> 4) * 8;

    f32x4 acc[8];
    #pragma unroll
    for (int nt = 0; nt < 8; ++nt) acc[nt] = (f32x4){0.f, 0.f, 0.f, 0.f};

    #pragma unroll
    for (int kt = 0; kt < 4; ++kt) {
        float4 a0 = *(const float4*)(xrow + kt * 32);
        float4 a1 = *(const float4*)(xrow + kt * 32 + 4);
        bf16x8 af;
        af[0] = (short)f2bf(a0.x); af[1] = (short)f2bf(a0.y);
        af[2] = (short)f2bf(a0.z); af[3] = (short)f2bf(a0.w);
        af[4] = (short)f2bf(a1.x); af[5] = (short)f2bf(a1.y);
        af[6] = (short)f2bf(a1.z); af[7] = (short)f2bf(a1.w);
        #pragma unroll
        for (int nt = 0; nt < 8; ++nt) {
            bf16x8 bf = *(const bf16x8*)&WF[kt][nt][lane][0];
            acc[nt] = __builtin_amdgcn_mfma_f32_16x16x32_bf16(af, bf, acc[nt], 0, 0, 0);
        }
    }

    const int drow0 = n0 + (lane >> 4) * 4;
    const int dcol  = lane & 15;
    #pragma unroll
    for (int nt = 0; nt < 8; ++nt) {
        #pragma unroll
        for (int r = 0; r < 4; ++r) {
            const int row = drow0 + r;
            if (row < N) {
                if (CHUNKED) {
                    // global col = nt*16 + dcol; chunk = nt>>1, ccol = (nt&1)*16 + dcol
                    y[((size_t)(nt >> 1) * N + row) * CW + (nt & 1) * 16 + dcol] = f2bf(acc[nt][r]);
                } else {
                    y[(size_t)row * F + nt * 16 + dcol] = f2bf(acc[nt][r]);
                }
            }
        }
    }
}

// ---------------------------------------------------------------------------
// K2: chunked gather-average, CW=32 (64 B rows). chunk = blockIdx & 3 -> each
// chunk pinned to an XCD pair via the HW round-robin block->XCD mapping.
// Block = 64 nodes; wave = 16 nodes as 4 groups x 16 lanes (lane j covers
// dword j of the 64 B row = 2 cols). 26 independent row reads in flight.
// idx staged in LDS; idx loads + out stores nontemporal.
// ---------------------------------------------------------------------------
__global__ __launch_bounds__(256) void gather_chunked(
    const ushort* __restrict__ y, const int* __restrict__ idx32,
    const float* __restrict__ bias, float* __restrict__ out, int N)
{
    __shared__ int IDX[64 * S];

    const int tid   = threadIdx.x;
    const int chunk = blockIdx.x & (CH - 1);
    const int tile  = blockIdx.x >> 2;
    const int nbase = tile * 64;
    const long total = (long)N * S;

    for (int e = tid; e < 64 * S; e += 256) {
        long p = (long)nbase * S + e;
        IDX[e] = (p < total) ? __builtin_nontemporal_load(&idx32[p]) : 0;
    }
    __syncthreads();

    const int lane = tid & 63, wave = tid >> 6;
    const int g = lane >> 4, j = lane & 15;        // 4 groups x 16 lanes
    const float2 bb = ((const float2*)bias)[chunk * (CW / 2) + j];
    const float inv = 1.0f / (float)(S + 1);
    const char* ycb = (const char*)(y + (size_t)chunk * N * CW);

    #pragma unroll
    for (int oct = 0; oct < 4; ++oct) {
        const int nl = wave * 16 + oct * 4 + g;   // node within tile
        const int n  = nbase + nl;
        const int nc = n < N ? n : 0;

        uint v[26];
        v[25] = *(const uint*)(ycb + (((uint)nc) << 6) + (j << 2));   // self
        #pragma unroll
        for (int s = 0; s < S; ++s) {
            int id = IDX[nl * S + s];
            v[s] = *(const uint*)(ycb + (((uint)id) << 6) + (j << 2));
        }

        float ax = 0.f, ay = 0.f;
        #pragma unroll
        for (int s = 0; s < 26; ++s) { ax += bf_lo(v[s]); ay += bf_hi(v[s]); }

        if (n < N) {
            f32x2 o;
            o.x = ax * inv + bb.x;
            o.y = ay * inv + bb.y;
            __builtin_nontemporal_store(o, (f32x2*)(out + (size_t)n * F + chunk * CW + 2 * j));
        }
    }
}

// ---------------------------------------------------------------------------
// Fallback A (ws fits y only): flat gather on row-major bf16 y.
// ---------------------------------------------------------------------------
__global__ __launch_bounds__(256) void gather_agg_bf16(
    const ushort* __restrict__ y, const int* __restrict__ nbr,
    const float* __restrict__ bias, float* __restrict__ out, int N)
{
    const int lane = threadIdx.x & 63;
    const int wid  = threadIdx.x >> 6;
    const bool is64 = idx_is_i64(nbr);
    const float2 bb = ((const float2*)bias)[lane];
    const float inv = 1.0f / (float)(S + 1);
    const int nw = gridDim.x * 4;
    const uint* yw = (const uint*)y;

    for (int n = blockIdx.x * 4 + wid; n < N; n += nw) {
        const int nu = __builtin_amdgcn_readfirstlane(n);
        int ids[S];
        #pragma unroll
        for (int s = 0; s < S; ++s)
            ids[s] = load_idx(nbr, (size_t)nu * S + s, is64);
        uint vs[S];
        #pragma unroll
        for (int s = 0; s < S; ++s)
            vs[s] = yw[(size_t)ids[s] * 64 + lane];
        const uint v0 = yw[(size_t)nu * 64 + lane];
        float ax = bf_lo(v0), ay = bf_hi(v0);
        #pragma unroll
        for (int s = 0; s < S; ++s) { ax += bf_lo(vs[s]); ay += bf_hi(vs[s]); }
        float2 o;
        o.x = ax * inv + bb.x;
        o.y = ay * inv + bb.y;
        ((float2*)(out + (size_t)nu * F))[lane] = o;
    }
}

// ---------------------------------------------------------------------------
// Fallback B (tiny ws): fused fp32 gather+GEMM.
// ---------------------------------------------------------------------------
__global__ __launch_bounds__(256) void fused_fallback_kernel(
    const float* __restrict__ x, const int* __restrict__ nbr,
    const float* __restrict__ W, const float* __restrict__ bias,
    float* __restrict__ out, int N)
{
    __shared__ float aggs[4][F];
    const int lane = threadIdx.x & 63;
    const int wid  = threadIdx.x >> 6;
    const bool is64 = idx_is_i64(nbr);
    const float inv = 1.0f / (float)(S + 1);
    const int stride = gridDim.x * 4;

    for (int base = blockIdx.x * 4; base < N; base += stride) {
        int n = base + wid;
        bool act = n < N;
        float2 acc = make_float2(0.f, 0.f);
        if (act) {
            acc = ((const float2*)(x + (size_t)n * F))[lane];
            for (int s = 0; s < S; ++s) {
                int id = load_idx(nbr, (size_t)n * S + s, is64);
                float2 v = ((const float2*)(x + (size_t)id * F))[lane];
                acc.x += v.x; acc.y += v.y;
            }
        }
        aggs[wid][2 * lane]     = acc.x * inv;
        aggs[wid][2 * lane + 1] = acc.y * inv;
        __syncthreads();
        if (act) {
            float o0 = bias[lane], o1 = bias[lane + 64];
            for (int k = 0; k < F; ++k) {
                float a = aggs[wid][k];
                o0 += a * W[k * F + lane];
                o1 += a * W[k * F + lane + 64];
            }
            out[(size_t)n * F + lane]      = o0;
            out[(size_t)n * F + lane + 64] = o1;
        }
        __syncthreads();
    }
}

extern "C" void kernel_launch(void* const* d_in, const int* in_sizes, int n_in,
                              void* d_out, int out_size, void* d_ws, size_t ws_size,
                              hipStream_t stream) {
    const float* x    = (const float*)d_in[0];
    const int*   nbr  = (const int*)d_in[1];
    const float* W    = (const float*)d_in[2];
    const float* bias = (const float*)d_in[3];
    float* out = (float*)d_out;
    const int N = in_sizes[0] / F;                 // 100000
    const int M = N * S;                           // 2.5M edges

    const size_t y_bytes   = (size_t)N * F * sizeof(ushort);   // 25.6 MB
    const size_t idx_bytes = (size_t)M * sizeof(int);          // 10 MB

    if (ws_size >= y_bytes + idx_bytes) {
        ushort* y   = (ushort*)d_ws;
        int*  idx32 = (int*)((char*)d_ws + y_bytes);
        compact_idx<<<(M + 255) / 256, 256, 0, stream>>>(nbr, idx32, M);
        gemm_xw_bf16<1><<<(N + 63) / 64, 256, 0, stream>>>(x, W, y, N);
        const int tiles = (N + 63) / 64;           // 1563
        gather_chunked<<<tiles * CH, 256, 0, stream>>>(y, idx32, bias, out, N);
    } else if (ws_size >= y_bytes) {
        ushort* y = (ushort*)d_ws;
        gemm_xw_bf16<0><<<(N + 63) / 64, 256, 0, stream>>>(x, W, y, N);
        gather_agg_bf16<<<2048, 256, 0, stream>>>(y, nbr, bias, out, N);
    } else {
        fused_fallback_kernel<<<2048, 256, 0, stream>>>(x, nbr, W, bias, out, N);
    }
}